// Round 13
// baseline (383.315 us; speedup 1.0000x reference)
//
#include <hip/hip_runtime.h>

#define ROWS_TOTAL 131072
#define XST 224             // g_xb row stride in bf16 elements (448 B, zero-padded)

typedef float f32x4 __attribute__((ext_vector_type(4)));
typedef short s16x8 __attribute__((ext_vector_type(8)));

// W fragment-linear, per 112-col group:
//   ushort idx = ((cg*7 + kk)*112 + col112)*32 + ks*8 + e   (zero-padded k>=196)
__device__ unsigned short g_Wb3[7 * 7 * 112 * 32];          // 351 KB
// x patchified, bf16, row stride 224 ushorts (zero-padded k = 196..223)
__device__ unsigned short g_xb[(size_t)ROWS_TOTAL * XST];   // 58.7 MB

__device__ __forceinline__ unsigned short f2bf(float f) {
    unsigned int u = __builtin_bit_cast(unsigned int, f);
    u += 0x7fffu + ((u >> 16) & 1u);        // round-to-nearest-even
    return (unsigned short)(u >> 16);
}

__global__ void prep_w(const float* __restrict__ W) {
    int t = blockIdx.x * 256 + threadIdx.x;   // 784 cols * 56 k-quads
    if (t >= 784 * 56) return;
    int col = t / 56;
    int k0  = (t - col * 56) * 4;
    uint2 pk;
    if (k0 < 196) {
        f32x4 d = *(const f32x4*)(W + col * 196 + k0);
        pk.x = (unsigned int)f2bf(d[0]) | ((unsigned int)f2bf(d[1]) << 16);
        pk.y = (unsigned int)f2bf(d[2]) | ((unsigned int)f2bf(d[3]) << 16);
    } else {
        pk.x = 0u; pk.y = 0u;
    }
    int cg = col / 112, col112 = col - cg * 112;
    int kk = k0 >> 5, rem = k0 & 31, ks = rem >> 3, e0 = rem & 7;
    size_t di = (size_t)(((cg * 7 + kk) * 112 + col112)) * 32 + ks * 8 + e0;
    *(uint2*)(g_Wb3 + di) = pk;
}

// patchify: x[32768,28,28] fp32 -> g_xb[131072][224] bf16 (zero-padded)
__global__ void prep_x(const float* __restrict__ x) {
    const int NV = ROWS_TOTAL / 4 * 784 / 4;            // 6,422,528 float4s
    const f32x4* xv = (const f32x4*)x;
    for (int v = blockIdx.x * 256 + threadIdx.x; v < NV; v += gridDim.x * 256) {
        f32x4 d = xv[v];
        int F   = v * 4;
        int img = F / 784;
        int rem = F - img * 784;
        int h   = rem / 28;
        int w0  = rem - h * 28;          // in {0,4,...,24}
        int ph  = h / 14;
        int r   = h - ph * 14;
        int rowb = img * 4 + ph * 2;
        #pragma unroll
        for (int p = 0; p < 2; ++p) {
            int w  = w0 + 2 * p;         // even => bf16 pair stays inside one patch
            int pw = (w >= 14) ? 1 : 0;
            int c  = w - pw * 14;
            int row = rowb + pw;
            unsigned int pack = (unsigned int)f2bf(d[2 * p]) |
                                ((unsigned int)f2bf(d[2 * p + 1]) << 16);
            *(unsigned int*)((char*)g_xb + (size_t)row * (XST * 2) + (r * 14 + c) * 2) = pack;
        }
    }
    // zero pad k = 196..223 for every row
    for (int t = blockIdx.x * 256 + threadIdx.x; t < ROWS_TOTAL * 7; t += gridDim.x * 256) {
        int row = t / 7;
        int j   = t - row * 7;
        *(uint2*)((char*)g_xb + (size_t)row * (XST * 2) + 392 + j * 8) = (uint2){0u, 0u};
    }
}

__device__ __forceinline__ void gload_lds16(void* lds, const void* g) {
    __builtin_amdgcn_global_load_lds(
        (const __attribute__((address_space(1))) unsigned int*)g,
        (__attribute__((address_space(3))) unsigned int*)lds, 16, 0, 0);
}

// Persistent-ish block: cg FIXED, sW staged once (read-only after one barrier),
// then 4 barrier-free iterations over 128-row tiles: prefetch xf(it+1) into the
// alternate reg buffer || 49 ds_read + 98 MFMA on xf(it) || 14 burst stores.
// Counted vmcnt (compiler) keeps stores+loads in flight under MFMA. 8 waves/CU.
// Grid order g = xcd + 8*(j*7+cg): the 7 cg-siblings of a row-slice run
// concurrently on one XCD -> output 128B lines complete quickly in that L2.
__global__ __launch_bounds__(256, 2)
void patch_linear_mfma(const float* __restrict__ blin,
                       float* __restrict__ out) {
    __shared__ __align__(16) char sW[49 * 1024];   // [kk][col112][ks][16B]

    const int tid  = threadIdx.x;
    const int l    = tid & 63;
    const int wv   = tid >> 6;          // 0..3
    const int lrow = l & 15;
    const int lk   = l >> 4;

    // g = xcd + 8*(j*7 + cg): xcd 0..7, j 0..31, cg 0..6
    const int g   = blockIdx.x;
    const int xcd = g & 7;
    const int t   = g >> 3;             // 0..223
    const int j   = t / 7;
    const int cg  = t - j * 7;
    const size_t row0 = ((size_t)xcd * 32 + j) * 512;   // block owns 512 rows

    // ---- stage W group once: 49 x 1 KiB linear async DMA ----
    const char* wsrc = (const char*)g_Wb3 + (size_t)cg * 50176 + l * 16;
    #pragma unroll
    for (int c = 0; c < 13; ++c) {
        int ch = wv + c * 4;
        if (ch < 49) gload_lds16(sW + ch * 1024, wsrc + ch * 1024);
    }

    // bias regs (cg fixed)
    f32x4 bias[7];
    #pragma unroll
    for (int n = 0; n < 7; ++n)
        bias[n] = *(const f32x4*)(blin + cg * 112 + n * 16 + lk * 4);

    const char* xfbase = (const char*)g_xb +
                         (row0 + wv * 32 + lrow) * 448 + lk * 16;
    float* outbase = out + (row0 + wv * 32 + lrow) * 784 + cg * 112 + lk * 4;
    const char* wb = sW + lrow * 64 + lk * 16;

    s16x8 xfA[2][7], xfB[2][7];

    // prologue: xf for iteration 0
    #pragma unroll
    for (int m = 0; m < 2; ++m)
        #pragma unroll
        for (int kk = 0; kk < 7; ++kk)
            xfA[m][kk] = *(const s16x8*)(xfbase + m * (16 * 448) + kk * 64);

    __syncthreads();   // sW ready; the ONLY block-wide barrier

    auto iter = [&](s16x8 (&xc)[2][7], s16x8* xn, int it) {
        if (xn) {   // prefetch next tile's x fragments (independent, flies under MFMA)
            const char* xp = xfbase + (size_t)(it + 1) * (128 * 448);
            #pragma unroll
            for (int m = 0; m < 2; ++m)
                #pragma unroll
                for (int kk = 0; kk < 7; ++kk)
                    xn[m * 7 + kk] = *(const s16x8*)(xp + m * (16 * 448) + kk * 64);
        }
        f32x4 acc[2][7];
        #pragma unroll
        for (int n = 0; n < 7; ++n) { acc[0][n] = bias[n]; acc[1][n] = bias[n]; }
        #pragma unroll
        for (int kk = 0; kk < 7; ++kk)
            #pragma unroll
            for (int n = 0; n < 7; ++n) {
                s16x8 wf = *(const s16x8*)(wb + kk * 7168 + n * 1024);
                acc[0][n] = __builtin_amdgcn_mfma_f32_16x16x32_bf16(wf, xc[0][kk], acc[0][n], 0, 0, 0);
                acc[1][n] = __builtin_amdgcn_mfma_f32_16x16x32_bf16(wf, xc[1][kk], acc[1][n], 0, 0, 0);
            }
        float* orow = outbase + (size_t)it * (128 * 784);
        #pragma unroll
        for (int m = 0; m < 2; ++m)
            #pragma unroll
            for (int n = 0; n < 7; ++n)
                *(f32x4*)(orow + m * (16 * 784) + n * 16) = acc[m][n];
    };

    iter(xfA, &xfB[0][0], 0);
    iter(xfB, &xfA[0][0], 1);
    iter(xfA, &xfB[0][0], 2);
    iter(xfB, nullptr,    3);
}

extern "C" void kernel_launch(void* const* d_in, const int* in_sizes, int n_in,
                              void* d_out, int out_size, void* d_ws, size_t ws_size,
                              hipStream_t stream) {
    const float* x    = (const float*)d_in[0];   // [32768,1,28,28]
    const float* Wlin = (const float*)d_in[1];   // [784,196]
    const float* blin = (const float*)d_in[2];   // [784]
    float* out = (float*)d_out;                  // [32768,4,784]

    prep_w<<<(784 * 56 + 255) / 256, 256, 0, stream>>>(Wlin);
    prep_x<<<4096, 256, 0, stream>>>(x);

    dim3 grid(1792);                             // 8 xcd * 32 slices * 7 cg
    dim3 block(256);
    patch_linear_mfma<<<grid, block, 0, stream>>>(blin, out);
}

// Round 14
// 190.952 us; speedup vs baseline: 2.0074x; 2.0074x over previous
//
#include <hip/hip_runtime.h>

#define ROWS_TOTAL 131072
#define XST 224             // g_xb row stride in bf16 elements (448 B, zero-padded)
#define T_TILES 4           // 128-row tiles per block

typedef float f32x4 __attribute__((ext_vector_type(4)));
typedef short s16x8 __attribute__((ext_vector_type(8)));

// W fragment-linear, per 112-col group:
//   ushort idx = ((cg*7 + kk)*112 + col112)*32 + ks*8 + e   (zero-padded k>=196)
__device__ unsigned short g_Wb3[7 * 7 * 112 * 32];          // 351 KB
// x patchified, bf16, row stride 224 ushorts (zero-padded k = 196..223)
__device__ unsigned short g_xb[(size_t)ROWS_TOTAL * XST];   // 58.7 MB

__device__ __forceinline__ unsigned short f2bf(float f) {
    unsigned int u = __builtin_bit_cast(unsigned int, f);
    u += 0x7fffu + ((u >> 16) & 1u);        // round-to-nearest-even
    return (unsigned short)(u >> 16);
}

__global__ void prep_w(const float* __restrict__ W) {
    int t = blockIdx.x * 256 + threadIdx.x;   // 784 cols * 56 k-quads
    if (t >= 784 * 56) return;
    int col = t / 56;
    int k0  = (t - col * 56) * 4;
    uint2 pk;
    if (k0 < 196) {
        f32x4 d = *(const f32x4*)(W + col * 196 + k0);
        pk.x = (unsigned int)f2bf(d[0]) | ((unsigned int)f2bf(d[1]) << 16);
        pk.y = (unsigned int)f2bf(d[2]) | ((unsigned int)f2bf(d[3]) << 16);
    } else {
        pk.x = 0u; pk.y = 0u;
    }
    int cg = col / 112, col112 = col - cg * 112;
    int kk = k0 >> 5, rem = k0 & 31, ks = rem >> 3, e0 = rem & 7;
    size_t di = (size_t)(((cg * 7 + kk) * 112 + col112)) * 32 + ks * 8 + e0;
    *(uint2*)(g_Wb3 + di) = pk;
}

// patchify: x[32768,28,28] fp32 -> g_xb[131072][224] bf16 (zero-padded)
__global__ void prep_x(const float* __restrict__ x) {
    const int NV = ROWS_TOTAL / 4 * 784 / 4;            // 6,422,528 float4s
    const f32x4* xv = (const f32x4*)x;
    for (int v = blockIdx.x * 256 + threadIdx.x; v < NV; v += gridDim.x * 256) {
        f32x4 d = xv[v];
        int F   = v * 4;
        int img = F / 784;
        int rem = F - img * 784;
        int h   = rem / 28;
        int w0  = rem - h * 28;          // in {0,4,...,24}
        int ph  = h / 14;
        int r   = h - ph * 14;
        int rowb = img * 4 + ph * 2;
        #pragma unroll
        for (int p = 0; p < 2; ++p) {
            int w  = w0 + 2 * p;         // even => bf16 pair stays inside one patch
            int pw = (w >= 14) ? 1 : 0;
            int c  = w - pw * 14;
            int row = rowb + pw;
            unsigned int pack = (unsigned int)f2bf(d[2 * p]) |
                                ((unsigned int)f2bf(d[2 * p + 1]) << 16);
            *(unsigned int*)((char*)g_xb + (size_t)row * (XST * 2) + (r * 14 + c) * 2) = pack;
        }
    }
    // zero pad k = 196..223 for every row
    for (int t = blockIdx.x * 256 + threadIdx.x; t < ROWS_TOTAL * 7; t += gridDim.x * 256) {
        int row = t / 7;
        int j   = t - row * 7;
        *(uint2*)((char*)g_xb + (size_t)row * (XST * 2) + 392 + j * 8) = (uint2){0u, 0u};
    }
}

__device__ __forceinline__ void gload_lds16(void* lds, const void* g) {
    __builtin_amdgcn_global_load_lds(
        (const __attribute__((address_space(1))) unsigned int*)g,
        (__attribute__((address_space(3))) unsigned int*)lds, 16, 0, 0);
}

// Block: cg fixed, sW staged ONCE (read-only; one barrier total), then a
// runtime loop over T_TILES 128-row tiles: {14 xf reg-loads -> 49 ds_read +
// 98 MFMA -> 14 burst stores}. All reg arrays use literal indices only
// (inner loops fully unrolled; no pointers/lambdas) -> no scratch.
// After the barrier waves free-run and drift -> continuous store stream.
// Sibling cg blocks launch-adjacent (bid = cg + 7*slice); L3 serves x re-reads.
__global__ __launch_bounds__(256, 2)
void patch_linear_mfma(const float* __restrict__ blin,
                       float* __restrict__ out) {
    __shared__ __align__(16) char sW[49 * 1024];   // [kk][col112][ks][16B]

    const int tid  = threadIdx.x;
    const int l    = tid & 63;
    const int wv   = tid >> 6;          // 0..3
    const int lrow = l & 15;
    const int lk   = l >> 4;

    const int bid   = blockIdx.x;
    const int slice = bid / 7;          // 0..255
    const int cg    = bid - slice * 7;  // 0..6
    const size_t row0 = (size_t)slice * (T_TILES * 128);

    // ---- stage W group once: 49 x 1 KiB linear async DMA ----
    const char* wsrc = (const char*)g_Wb3 + (size_t)cg * 50176 + l * 16;
    #pragma unroll
    for (int c = 0; c < 13; ++c) {
        int ch = wv + c * 4;
        if (ch < 49) gload_lds16(sW + ch * 1024, wsrc + ch * 1024);
    }

    // bias regs (cg fixed)
    f32x4 bias[7];
    #pragma unroll
    for (int n = 0; n < 7; ++n)
        bias[n] = *(const f32x4*)(blin + cg * 112 + n * 16 + lk * 4);

    __syncthreads();   // sW ready; the ONLY barrier

    const char* wb = sW + lrow * 64 + lk * 16;

    for (int t = 0; t < T_TILES; ++t) {
        const size_t r = row0 + (size_t)t * 128 + wv * 32 + lrow;

        // x fragments -> registers (ds_reads below overlap this latency)
        const char* xb = (const char*)g_xb + r * 448 + lk * 16;
        s16x8 xf[2][7];
        #pragma unroll
        for (int m = 0; m < 2; ++m)
            #pragma unroll
            for (int kk = 0; kk < 7; ++kk)
                xf[m][kk] = *(const s16x8*)(xb + m * (16 * 448) + kk * 64);

        f32x4 acc[2][7];
        #pragma unroll
        for (int n = 0; n < 7; ++n) { acc[0][n] = bias[n]; acc[1][n] = bias[n]; }

        #pragma unroll
        for (int kk = 0; kk < 7; ++kk)
            #pragma unroll
            for (int n = 0; n < 7; ++n) {
                s16x8 wf = *(const s16x8*)(wb + kk * 7168 + n * 1024);
                acc[0][n] = __builtin_amdgcn_mfma_f32_16x16x32_bf16(wf, xf[0][kk], acc[0][n], 0, 0, 0);
                acc[1][n] = __builtin_amdgcn_mfma_f32_16x16x32_bf16(wf, xf[1][kk], acc[1][n], 0, 0, 0);
            }

        // store: 14 dwordx4/lane, full aligned 64-B sectors
        float* orow = out + r * 784 + cg * 112 + lk * 4;
        #pragma unroll
        for (int m = 0; m < 2; ++m)
            #pragma unroll
            for (int n = 0; n < 7; ++n)
                *(f32x4*)(orow + m * (16 * 784) + n * 16) = acc[m][n];
    }
}

extern "C" void kernel_launch(void* const* d_in, const int* in_sizes, int n_in,
                              void* d_out, int out_size, void* d_ws, size_t ws_size,
                              hipStream_t stream) {
    const float* x    = (const float*)d_in[0];   // [32768,1,28,28]
    const float* Wlin = (const float*)d_in[1];   // [784,196]
    const float* blin = (const float*)d_in[2];   // [784]
    float* out = (float*)d_out;                  // [32768,4,784]

    prep_w<<<(784 * 56 + 255) / 256, 256, 0, stream>>>(Wlin);
    prep_x<<<4096, 256, 0, stream>>>(x);

    dim3 grid(256 * 7);                          // 1792 blocks: bid = cg + 7*slice
    dim3 block(256);
    patch_linear_mfma<<<grid, block, 0, stream>>>(blin, out);
}